// Round 7
// baseline (410.401 us; speedup 1.0000x reference)
//
#include <hip/hip_runtime.h>
#include <math.h>

#define B 64
#define S 2048
#define D 512
#define H 512

typedef _Float16 f16x8 __attribute__((ext_vector_type(8)));
typedef __fp16 fp16x2 __attribute__((ext_vector_type(2)));
typedef float f32x4 __attribute__((ext_vector_type(4)));

#define WSC 128  // s-rows per k_wsum chunk

// ws layout: [0,512K) packed Wc fp16; [512K,512K+2M) wsum partials f32 [16][B][D];
//            then 4 B mask count
#define WS_PART_OFF (512 * 1024)
#define WS_CNT_OFF  (512 * 1024 + 2 * 1024 * 1024)

// ---------------------------------------------------------------------------
// K0: pack Wc (fp32 [H][D]) -> fp16 in MFMA-fragment order; also zero cnt.
//   slot = kt*2048 + hg*64 + lane ; holds Wc[hg*16 + (lane&15)][kt*32 + (lane>>4)*8 + j]
// ---------------------------------------------------------------------------
__global__ __launch_bounds__(256) void k_pack_wc(
        const float* __restrict__ Wc, _Float16* __restrict__ wsB,
        int* __restrict__ cnt) {
    if (blockIdx.x == 0 && threadIdx.x == 0) *cnt = 0;
    const int slot = blockIdx.x * 256 + threadIdx.x;   // 0..32767
    const int kt   = slot >> 11;
    const int rem  = slot & 2047;
    const int hg   = rem >> 6;
    const int lane = rem & 63;
    const int h  = hg * 16 + (lane & 15);
    const int k0 = kt * 32 + (lane >> 4) * 8;
    const float* src = Wc + (size_t)h * D + k0;
    float4 f0 = *(const float4*)src;
    float4 f1 = *(const float4*)(src + 4);
    f16x8 v;
    v[0] = (_Float16)f0.x; v[1] = (_Float16)f0.y;
    v[2] = (_Float16)f0.z; v[3] = (_Float16)f0.w;
    v[4] = (_Float16)f1.x; v[5] = (_Float16)f1.y;
    v[6] = (_Float16)f1.z; v[7] = (_Float16)f1.w;
    *(f16x8*)(wsB + (size_t)slot * 8) = v;
}

// ---------------------------------------------------------------------------
// K0b: global mask count (cnt pre-zeroed by k_pack_wc earlier on the stream)
// ---------------------------------------------------------------------------
__global__ __launch_bounds__(256) void k_mask_count(
        const int* __restrict__ mask, int* __restrict__ cnt) {
    const int base = blockIdx.x * 256 + threadIdx.x;
    int local = 0;
    for (int i = base; i < B * S; i += 256 * 64) local += (mask[i] != 0) ? 1 : 0;
    #pragma unroll
    for (int off = 32; off; off >>= 1) local += __shfl_down(local, off, 64);
    if ((threadIdx.x & 63) == 0 && local) atomicAdd(cnt, local);
}

// ---------------------------------------------------------------------------
// K1: inp = input @ W_in^T + b_in   -> staged in d_out hidden region
// ---------------------------------------------------------------------------
__global__ __launch_bounds__(256) void k_input_linear(
        const float* __restrict__ input,
        const float* __restrict__ W_in,
        const float* __restrict__ b_in,
        float* __restrict__ out_inp) {
    const int b = blockIdx.x;
    const int tid = threadIdx.x;
    __shared__ float xrow[D];
    for (int d = tid; d < D; d += 256) xrow[d] = input[(size_t)b * D + d];
    __syncthreads();
    for (int h = tid; h < H; h += 256) {
        const float* w = W_in + (size_t)h * D;
        float acc = 0.f;
        #pragma unroll 4
        for (int d = 0; d < D; d += 4) {
            float4 wv = *(const float4*)(w + d);
            acc += wv.x * xrow[d] + wv.y * xrow[d + 1] + wv.z * xrow[d + 2] + wv.w * xrow[d + 3];
        }
        out_inp[(size_t)b * H + h] = acc + b_in[h];
    }
}

// ---------------------------------------------------------------------------
// K2 (MFMA): fused ctx-GEMM + tanh + V-reduce. ZERO-LDS, ZERO-BARRIER K-loop.
//   Block: 64 s-rows x full H=512. 8 waves, wave tile 64s x 64h.
//   A fragments read DIRECTLY from global ctx (16 rows x 128 B per frag ->
//   perfectly line-coalesced; 8x block redundancy absorbed by L1) and
//   converted in-register. B frags from packed-Wc global (L2-resident).
//   Waves fully independent until the tiny epilogue reduction.
// ---------------------------------------------------------------------------
__global__ __launch_bounds__(512, 4) void k_energy(
        const float* __restrict__ ctx,
        const _Float16* __restrict__ WcP,
        const float* __restrict__ bc,
        const float* __restrict__ inp,
        const float* __restrict__ V,
        float* __restrict__ att) {
    __shared__ float red[8][64];

    const int tid = threadIdx.x;
    const int b  = blockIdx.x >> 5;             // 32 s-tiles per batch
    const int s0 = (blockIdx.x & 31) << 6;

    const int lane = tid & 63;
    const int w    = tid >> 6;      // 0..7: h-slice (64 h each)
    const int lrow = lane & 15;
    const int kblk = lane >> 4;     // 0..3

    f32x4 acc[4][4] = {};

    // A: lane reads ctx[s0 + m*16 + lrow][kt*32 + kblk*8 .. +8)
    const float* Abase = ctx + ((size_t)b * S + s0 + lrow) * D + kblk * 8;
    const _Float16* Bbase = WcP + ((size_t)(w * 4) * 64 + lane) * 8;

    #pragma unroll 1
    for (int kt = 0; kt < 16; ++kt) {
        // B frags (L2, coalesced 1 KB/instr)
        f16x8 bfr[4];
        #pragma unroll
        for (int n = 0; n < 4; ++n)
            bfr[n] = *(const f16x8*)(Bbase + ((size_t)kt * 2048 + n * 64) * 8);

        // A frags: direct global load + in-register cvt
        f16x8 afr[4];
        #pragma unroll
        for (int m = 0; m < 4; ++m) {
            const float* src = Abase + (size_t)(m * 16) * D + kt * 32;
            float4 f0 = *(const float4*)src;
            float4 f1 = *(const float4*)(src + 4);
            union { fp16x2 h2[4]; f16x8 v; } u;
            u.h2[0] = __builtin_amdgcn_cvt_pkrtz(f0.x, f0.y);
            u.h2[1] = __builtin_amdgcn_cvt_pkrtz(f0.z, f0.w);
            u.h2[2] = __builtin_amdgcn_cvt_pkrtz(f1.x, f1.y);
            u.h2[3] = __builtin_amdgcn_cvt_pkrtz(f1.z, f1.w);
            afr[m] = u.v;
        }

        #pragma unroll
        for (int m = 0; m < 4; ++m)
            #pragma unroll
            for (int n = 0; n < 4; ++n)
                acc[m][n] = __builtin_amdgcn_mfma_f32_16x16x32_f16(afr[m], bfr[n], acc[m][n], 0, 0, 0);
    }

    // ---- epilogue: tanh + V weighting; reduce over this wave's 64 h ----
    float ps[4][4] = {};   // [m][reg]
    #pragma unroll
    for (int n = 0; n < 4; ++n) {
        const int h = w * 64 + n * 16 + lrow;
        const float ib = inp[(size_t)b * H + h] + bc[h];
        const float v = V[h];
        #pragma unroll
        for (int m = 0; m < 4; ++m)
            #pragma unroll
            for (int r = 0; r < 4; ++r) {
                const float x = acc[m][n][r] + ib;
                const float t = 1.f - 2.f / (1.f + __expf(2.f * x));
                ps[m][r] += v * t;
            }
    }
    #pragma unroll
    for (int off = 1; off < 16; off <<= 1)
        #pragma unroll
        for (int m = 0; m < 4; ++m)
            #pragma unroll
            for (int r = 0; r < 4; ++r)
                ps[m][r] += __shfl_xor(ps[m][r], off, 64);
    if (lrow == 0) {
        #pragma unroll
        for (int m = 0; m < 4; ++m)
            #pragma unroll
            for (int r = 0; r < 4; ++r)
                red[w][m * 16 + kblk * 4 + r] = ps[m][r];
    }
    __syncthreads();
    if (tid < 64) {
        float sum = 0.f;
        #pragma unroll
        for (int i = 0; i < 8; ++i) sum += red[i][tid];
        att[(size_t)b * S + s0 + tid] = sum;
    }
}

// ---------------------------------------------------------------------------
// K4: mask branch + softmax per row (in place in the alpha region).
// ---------------------------------------------------------------------------
__global__ __launch_bounds__(256) void k_softmax(
        const int* __restrict__ mask,
        const float* __restrict__ amask,
        const int* __restrict__ cnt,
        float* __restrict__ att) {
    const int b = blockIdx.x;
    const int tid = threadIdx.x;
    __shared__ float sh[S];
    __shared__ float fredm[4];
    __shared__ float freds[4];

    const int n_true = *cnt;
    const bool inf_branch = (n_true > 0) && (n_true == S);

    const float NEG_INF = -__builtin_inff();
    for (int s = tid; s < S; s += 256) {
        const float raw = att[(size_t)b * S + s];
        float v;
        if (inf_branch)
            v = mask[(size_t)b * S + s] ? NEG_INF : raw;
        else
            v = raw * amask[(size_t)b * S + s];
        sh[s] = v;
    }
    __syncthreads();

    float mx = NEG_INF;
    for (int s = tid; s < S; s += 256) mx = fmaxf(mx, sh[s]);
    #pragma unroll
    for (int off = 32; off; off >>= 1) mx = fmaxf(mx, __shfl_down(mx, off, 64));
    if ((tid & 63) == 0) fredm[tid >> 6] = mx;
    __syncthreads();
    mx = fmaxf(fmaxf(fredm[0], fredm[1]), fmaxf(fredm[2], fredm[3]));

    float lsum = 0.f;
    for (int s = tid; s < S; s += 256) {
        const float e = expf(sh[s] - mx);
        sh[s] = e;
        lsum += e;
    }
    #pragma unroll
    for (int off = 32; off; off >>= 1) lsum += __shfl_down(lsum, off, 64);
    if ((tid & 63) == 0) freds[tid >> 6] = lsum;
    __syncthreads();
    const float total = freds[0] + freds[1] + freds[2] + freds[3];
    const float rinv = 1.f / total;

    for (int s = tid; s < S; s += 256)
        att[(size_t)b * S + s] = sh[s] * rinv;
}

// ---------------------------------------------------------------------------
// K5: part[chunk][b][:] = sum_{s in chunk} alpha[b,s] * ctx[b,s,:]
//     (no atomics, no pre-zero; fully written each call)
// ---------------------------------------------------------------------------
__global__ __launch_bounds__(256) void k_wsum(
        const float* __restrict__ ctx,
        const float* __restrict__ alpha,
        float* __restrict__ part) {
    const int chunk = blockIdx.x & 15;
    const int b = blockIdx.x >> 4;
    const int s0 = chunk * WSC;
    const int tid = threadIdx.x;
    __shared__ float al[WSC];
    if (tid < WSC) al[tid] = alpha[(size_t)b * S + s0 + tid];
    __syncthreads();

    const int half = tid >> 7;
    const int dq = (tid & 127) * 4;
    const float* base = ctx + ((size_t)b * S + s0 + half) * D + dq;
    float4 acc = {0.f, 0.f, 0.f, 0.f};
    #pragma unroll 4
    for (int i = 0; i < WSC / 2; ++i) {
        float4 v = *(const float4*)(base + (size_t)i * 2 * D);
        const float a = al[i * 2 + half];
        acc.x += a * v.x; acc.y += a * v.y; acc.z += a * v.z; acc.w += a * v.w;
    }
    __shared__ float cb[2][D];
    *(float4*)&cb[half][dq] = acc;
    __syncthreads();
    if (tid < 128) {
        const int d = tid * 4;
        float4 p0 = *(const float4*)&cb[0][d];
        float4 p1 = *(const float4*)&cb[1][d];
        float4 o = {p0.x + p1.x, p0.y + p1.y, p0.z + p1.z, p0.w + p1.w};
        *(float4*)(part + ((size_t)chunk * B + b) * D + d) = o;
    }
}

// ---------------------------------------------------------------------------
// K6: hidden = Wc @ (sum of partials) + bc   (tiny GEMV per batch)
// ---------------------------------------------------------------------------
__global__ __launch_bounds__(256) void k_out(
        const float* __restrict__ part,
        const float* __restrict__ Wc,
        const float* __restrict__ bc,
        float* __restrict__ hidden) {
    const int b = blockIdx.x;
    const int tid = threadIdx.x;
    __shared__ float cb[D];
    for (int d = tid; d < D; d += 256) {
        float s = 0.f;
        #pragma unroll
        for (int c = 0; c < 16; ++c)
            s += part[((size_t)c * B + b) * D + d];
        cb[d] = s;
    }
    __syncthreads();
    for (int h = tid; h < H; h += 256) {
        const float* w = Wc + (size_t)h * D;
        float acc = 0.f;
        #pragma unroll 4
        for (int d = 0; d < D; d += 4) {
            float4 wv = *(const float4*)(w + d);
            acc += wv.x * cb[d] + wv.y * cb[d + 1] + wv.z * cb[d + 2] + wv.w * cb[d + 3];
        }
        hidden[(size_t)b * H + h] = acc + bc[h];
    }
}

// ---------------------------------------------------------------------------
extern "C" void kernel_launch(void* const* d_in, const int* in_sizes, int n_in,
                              void* d_out, int out_size, void* d_ws, size_t ws_size,
                              hipStream_t stream) {
    const float* input = (const float*)d_in[0];
    const float* ctx   = (const float*)d_in[1];
    const float* amask = (const float*)d_in[2];
    const float* W_in  = (const float*)d_in[3];
    const float* b_in  = (const float*)d_in[4];
    const float* W_ctx = (const float*)d_in[5];
    const float* b_ctx = (const float*)d_in[6];
    const float* V     = (const float*)d_in[7];
    const int*   mask  = (const int*)d_in[8];

    float* out = (float*)d_out;
    float* hidden = out;            // [B,H]
    float* alpha  = out + B * H;    // [B,S]

    _Float16* wsB  = (_Float16*)d_ws;
    float*    part = (float*)((char*)d_ws + WS_PART_OFF);
    int*      cnt  = (int*)((char*)d_ws + WS_CNT_OFF);

    // K0: pack Wc -> fp16 fragment order (+ zero cnt); K0b: mask count
    k_pack_wc<<<dim3(128), dim3(256), 0, stream>>>(W_ctx, wsB, cnt);
    k_mask_count<<<dim3(64), dim3(256), 0, stream>>>(mask, cnt);

    // K1: inp staged in the hidden region (overwritten later by real hidden)
    k_input_linear<<<dim3(B), dim3(256), 0, stream>>>(input, W_in, b_in, hidden);

    // K2: fused energy GEMM -> att (alpha region, direct store)
    k_energy<<<dim3(B * S / 64), dim3(512), 0, stream>>>(
        ctx, wsB, b_ctx, hidden, V, alpha);

    // K4: mask branch + softmax in place -> alpha final
    k_softmax<<<dim3(B), dim3(256), 0, stream>>>(mask, amask, cnt, alpha);

    // K5: weighted context partial sums -> part (no atomics)
    k_wsum<<<dim3(16 * B), dim3(256), 0, stream>>>(ctx, alpha, part);

    // K6: hidden = Wc @ sum(part) + bc
    k_out<<<dim3(B), dim3(256), 0, stream>>>(part, W_ctx, b_ctx, hidden);
}

// Round 8
// 236.036 us; speedup vs baseline: 1.7387x; 1.7387x over previous
//
#include <hip/hip_runtime.h>
#include <math.h>

#define B 64
#define S 2048
#define D 512
#define H 512

#define BK 64    // k per barrier interval (2 MFMA sub-phases of 32)
#define WSC 128  // s-rows per k_wsum chunk

typedef _Float16 f16x8 __attribute__((ext_vector_type(8)));
typedef __fp16 fp16x2 __attribute__((ext_vector_type(2)));
typedef float f32x4 __attribute__((ext_vector_type(4)));

// ws layout: [0,512K) packed Wc fp16; [512K,512K+2M) wsum partials f32 [16][B][D];
//            then 4 B mask count
#define WS_PART_OFF (512 * 1024)
#define WS_CNT_OFF  (512 * 1024 + 2 * 1024 * 1024)

// ---------------------------------------------------------------------------
// K0: pack Wc (fp32 [H][D]) -> fp16 in MFMA-fragment order; also zero cnt.
//   slot = st*2048 + hg*64 + lane ; holds Wc[hg*16 + (lane&15)][st*32 + (lane>>4)*8 + j]
// ---------------------------------------------------------------------------
__global__ __launch_bounds__(256) void k_pack_wc(
        const float* __restrict__ Wc, _Float16* __restrict__ wsB,
        int* __restrict__ cnt) {
    if (blockIdx.x == 0 && threadIdx.x == 0) *cnt = 0;
    const int slot = blockIdx.x * 256 + threadIdx.x;   // 0..32767
    const int st   = slot >> 11;
    const int rem  = slot & 2047;
    const int hg   = rem >> 6;
    const int lane = rem & 63;
    const int h  = hg * 16 + (lane & 15);
    const int k0 = st * 32 + (lane >> 4) * 8;
    const float* src = Wc + (size_t)h * D + k0;
    float4 f0 = *(const float4*)src;
    float4 f1 = *(const float4*)(src + 4);
    f16x8 v;
    v[0] = (_Float16)f0.x; v[1] = (_Float16)f0.y;
    v[2] = (_Float16)f0.z; v[3] = (_Float16)f0.w;
    v[4] = (_Float16)f1.x; v[5] = (_Float16)f1.y;
    v[6] = (_Float16)f1.z; v[7] = (_Float16)f1.w;
    *(f16x8*)(wsB + (size_t)slot * 8) = v;
}

// ---------------------------------------------------------------------------
// K0b: global mask count (cnt pre-zeroed by k_pack_wc earlier on the stream)
// ---------------------------------------------------------------------------
__global__ __launch_bounds__(256) void k_mask_count(
        const int* __restrict__ mask, int* __restrict__ cnt) {
    const int base = blockIdx.x * 256 + threadIdx.x;
    int local = 0;
    for (int i = base; i < B * S; i += 256 * 64) local += (mask[i] != 0) ? 1 : 0;
    #pragma unroll
    for (int off = 32; off; off >>= 1) local += __shfl_down(local, off, 64);
    if ((threadIdx.x & 63) == 0 && local) atomicAdd(cnt, local);
}

// ---------------------------------------------------------------------------
// K1: inp = input @ W_in^T + b_in   -> staged in d_out hidden region
// ---------------------------------------------------------------------------
__global__ __launch_bounds__(256) void k_input_linear(
        const float* __restrict__ input,
        const float* __restrict__ W_in,
        const float* __restrict__ b_in,
        float* __restrict__ out_inp) {
    const int b = blockIdx.x;
    const int tid = threadIdx.x;
    __shared__ float xrow[D];
    for (int d = tid; d < D; d += 256) xrow[d] = input[(size_t)b * D + d];
    __syncthreads();
    for (int h = tid; h < H; h += 256) {
        const float* w = W_in + (size_t)h * D;
        float acc = 0.f;
        #pragma unroll 4
        for (int d = 0; d < D; d += 4) {
            float4 wv = *(const float4*)(w + d);
            acc += wv.x * xrow[d] + wv.y * xrow[d + 1] + wv.z * xrow[d + 2] + wv.w * xrow[d + 3];
        }
        out_inp[(size_t)b * H + h] = acc + b_in[h];
    }
}

// ---------------------------------------------------------------------------
// K2 (MFMA): fused ctx-GEMM + tanh + V-reduce.
//   Block: 64 s-rows x full H=512 (ctx read once). 8 waves, wave 64s x 64h.
//   A: 64x64 fp16 tile, XOR-swizzled 16B slots (conflict-free), double
//   buffered, ONE barrier per BK=64 (2 MFMA sub-phases). B frags direct
//   from packed-Wc global (L2-resident). Direct att store.
// ---------------------------------------------------------------------------
__global__ __launch_bounds__(512, 4) void k_energy(
        const float* __restrict__ ctx,
        const _Float16* __restrict__ WcP,
        const float* __restrict__ bc,
        const float* __restrict__ inp,
        const float* __restrict__ V,
        float* __restrict__ att) {
    __shared__ alignas(16) _Float16 Alds[2][64 * BK];   // 2 x 8 KB
    __shared__ float red[8][64];

    const int tid = threadIdx.x;
    const int b  = blockIdx.x >> 5;             // 32 s-tiles per batch
    const int s0 = (blockIdx.x & 31) << 6;

    // staging roles: 8 threads per row, 8 floats (16 B fp16) each
    const int arow = tid >> 3;      // 0..63
    const int akq  = tid & 7;       // 0..7 -> slot before swizzle
    const int wslot = akq ^ (arow & 7);
    // compute roles
    const int lane = tid & 63;
    const int w    = tid >> 6;      // 0..7: h-slice (64 h each)
    const int lrow = lane & 15;
    const int kblk = lane >> 4;     // 0..3

    f32x4 acc[4][4] = {};

    const float* ctx_src = ctx + ((size_t)b * S + s0 + arow) * D + akq * 8;
    const _Float16* Bbase = WcP + ((size_t)(w * 4) * 64 + lane) * 8;

    // ---- prologue: stage A(0) into buf 0 ----
    {
        float4 f0 = *(const float4*)ctx_src;
        float4 f1 = *(const float4*)(ctx_src + 4);
        union { fp16x2 h2[4]; f16x8 v; } u;
        u.h2[0] = __builtin_amdgcn_cvt_pkrtz(f0.x, f0.y);
        u.h2[1] = __builtin_amdgcn_cvt_pkrtz(f0.z, f0.w);
        u.h2[2] = __builtin_amdgcn_cvt_pkrtz(f1.x, f1.y);
        u.h2[3] = __builtin_amdgcn_cvt_pkrtz(f1.z, f1.w);
        *(f16x8*)&Alds[0][arow * BK + wslot * 8] = u.v;
    }
    __syncthreads();

    #pragma unroll 1
    for (int kt = 0; kt < 8; ++kt) {
        const int cur = kt & 1;

        // T14: issue next A tile load early (consumed after the MFMAs)
        float4 nf0, nf1;
        if (kt < 7) {
            nf0 = *(const float4*)(ctx_src + (kt + 1) * BK);
            nf1 = *(const float4*)(ctx_src + (kt + 1) * BK + 4);
        }

        const _Float16* Ab = &Alds[cur][0];

        #pragma unroll
        for (int p = 0; p < 2; ++p) {
            const int st = kt * 2 + p;
            // B frags for this 32-k step (L2, coalesced 1 KB/instr)
            f16x8 bfr[4];
            #pragma unroll
            for (int n = 0; n < 4; ++n)
                bfr[n] = *(const f16x8*)(Bbase + ((size_t)st * 2048 + n * 64) * 8);

            // A frags from swizzled LDS
            const int sl = (p * 4 + kblk) ^ (lrow & 7);
            f16x8 afr[4];
            #pragma unroll
            for (int m = 0; m < 4; ++m)
                afr[m] = *(const f16x8*)(Ab + (m * 16 + lrow) * BK + sl * 8);

            #pragma unroll
            for (int m = 0; m < 4; ++m)
                #pragma unroll
                for (int n = 0; n < 4; ++n)
                    acc[m][n] = __builtin_amdgcn_mfma_f32_16x16x32_f16(afr[m], bfr[n], acc[m][n], 0, 0, 0);
        }

        // write next A tile to the other buffer
        if (kt < 7) {
            union { fp16x2 h2[4]; f16x8 v; } u;
            u.h2[0] = __builtin_amdgcn_cvt_pkrtz(nf0.x, nf0.y);
            u.h2[1] = __builtin_amdgcn_cvt_pkrtz(nf0.z, nf0.w);
            u.h2[2] = __builtin_amdgcn_cvt_pkrtz(nf1.x, nf1.y);
            u.h2[3] = __builtin_amdgcn_cvt_pkrtz(nf1.z, nf1.w);
            *(f16x8*)&Alds[cur ^ 1][arow * BK + wslot * 8] = u.v;
        }
        __syncthreads();
    }

    // ---- epilogue: tanh + V weighting; reduce over this wave's 64 h ----
    float ps[4][4] = {};   // [m][reg]
    #pragma unroll
    for (int n = 0; n < 4; ++n) {
        const int h = w * 64 + n * 16 + lrow;
        const float ib = inp[(size_t)b * H + h] + bc[h];
        const float v = V[h];
        #pragma unroll
        for (int m = 0; m < 4; ++m)
            #pragma unroll
            for (int r = 0; r < 4; ++r) {
                const float x = acc[m][n][r] + ib;
                const float t = 1.f - 2.f / (1.f + __expf(2.f * x));
                ps[m][r] += v * t;
            }
    }
    #pragma unroll
    for (int off = 1; off < 16; off <<= 1)
        #pragma unroll
        for (int m = 0; m < 4; ++m)
            #pragma unroll
            for (int r = 0; r < 4; ++r)
                ps[m][r] += __shfl_xor(ps[m][r], off, 64);
    if (lrow == 0) {
        #pragma unroll
        for (int m = 0; m < 4; ++m)
            #pragma unroll
            for (int r = 0; r < 4; ++r)
                red[w][m * 16 + kblk * 4 + r] = ps[m][r];
    }
    __syncthreads();
    if (tid < 64) {
        float sum = 0.f;
        #pragma unroll
        for (int i = 0; i < 8; ++i) sum += red[i][tid];
        att[(size_t)b * S + s0 + tid] = sum;
    }
}

// ---------------------------------------------------------------------------
// K4: mask branch + softmax per row (in place in the alpha region).
// ---------------------------------------------------------------------------
__global__ __launch_bounds__(256) void k_softmax(
        const int* __restrict__ mask,
        const float* __restrict__ amask,
        const int* __restrict__ cnt,
        float* __restrict__ att) {
    const int b = blockIdx.x;
    const int tid = threadIdx.x;
    __shared__ float sh[S];
    __shared__ float fredm[4];
    __shared__ float freds[4];

    const int n_true = *cnt;
    const bool inf_branch = (n_true > 0) && (n_true == S);

    const float NEG_INF = -__builtin_inff();
    for (int s = tid; s < S; s += 256) {
        const float raw = att[(size_t)b * S + s];
        float v;
        if (inf_branch)
            v = mask[(size_t)b * S + s] ? NEG_INF : raw;
        else
            v = raw * amask[(size_t)b * S + s];
        sh[s] = v;
    }
    __syncthreads();

    float mx = NEG_INF;
    for (int s = tid; s < S; s += 256) mx = fmaxf(mx, sh[s]);
    #pragma unroll
    for (int off = 32; off; off >>= 1) mx = fmaxf(mx, __shfl_down(mx, off, 64));
    if ((tid & 63) == 0) fredm[tid >> 6] = mx;
    __syncthreads();
    mx = fmaxf(fmaxf(fredm[0], fredm[1]), fmaxf(fredm[2], fredm[3]));

    float lsum = 0.f;
    for (int s = tid; s < S; s += 256) {
        const float e = expf(sh[s] - mx);
        sh[s] = e;
        lsum += e;
    }
    #pragma unroll
    for (int off = 32; off; off >>= 1) lsum += __shfl_down(lsum, off, 64);
    if ((tid & 63) == 0) freds[tid >> 6] = lsum;
    __syncthreads();
    const float total = freds[0] + freds[1] + freds[2] + freds[3];
    const float rinv = 1.f / total;

    for (int s = tid; s < S; s += 256)
        att[(size_t)b * S + s] = sh[s] * rinv;
}

// ---------------------------------------------------------------------------
// K5: part[chunk][b][:] = sum_{s in chunk} alpha[b,s] * ctx[b,s,:]
//     (no atomics, no pre-zero; fully written each call)
// ---------------------------------------------------------------------------
__global__ __launch_bounds__(256) void k_wsum(
        const float* __restrict__ ctx,
        const float* __restrict__ alpha,
        float* __restrict__ part) {
    const int chunk = blockIdx.x & 15;
    const int b = blockIdx.x >> 4;
    const int s0 = chunk * WSC;
    const int tid = threadIdx.x;
    __shared__ float al[WSC];
    if (tid < WSC) al[tid] = alpha[(size_t)b * S + s0 + tid];
    __syncthreads();

    const int half = tid >> 7;
    const int dq = (tid & 127) * 4;
    const float* base = ctx + ((size_t)b * S + s0 + half) * D + dq;
    float4 acc = {0.f, 0.f, 0.f, 0.f};
    #pragma unroll 4
    for (int i = 0; i < WSC / 2; ++i) {
        float4 v = *(const float4*)(base + (size_t)i * 2 * D);
        const float a = al[i * 2 + half];
        acc.x += a * v.x; acc.y += a * v.y; acc.z += a * v.z; acc.w += a * v.w;
    }
    __shared__ float cb[2][D];
    *(float4*)&cb[half][dq] = acc;
    __syncthreads();
    if (tid < 128) {
        const int d = tid * 4;
        float4 p0 = *(const float4*)&cb[0][d];
        float4 p1 = *(const float4*)&cb[1][d];
        float4 o = {p0.x + p1.x, p0.y + p1.y, p0.z + p1.z, p0.w + p1.w};
        *(float4*)(part + ((size_t)chunk * B + b) * D + d) = o;
    }
}

// ---------------------------------------------------------------------------
// K6: hidden = Wc @ (sum of partials) + bc   (tiny GEMV per batch)
// ---------------------------------------------------------------------------
__global__ __launch_bounds__(256) void k_out(
        const float* __restrict__ part,
        const float* __restrict__ Wc,
        const float* __restrict__ bc,
        float* __restrict__ hidden) {
    const int b = blockIdx.x;
    const int tid = threadIdx.x;
    __shared__ float cb[D];
    for (int d = tid; d < D; d += 256) {
        float s = 0.f;
        #pragma unroll
        for (int c = 0; c < 16; ++c)
            s += part[((size_t)c * B + b) * D + d];
        cb[d] = s;
    }
    __syncthreads();
    for (int h = tid; h < H; h += 256) {
        const float* w = Wc + (size_t)h * D;
        float acc = 0.f;
        #pragma unroll 4
        for (int d = 0; d < D; d += 4) {
            float4 wv = *(const float4*)(w + d);
            acc += wv.x * cb[d] + wv.y * cb[d + 1] + wv.z * cb[d + 2] + wv.w * cb[d + 3];
        }
        hidden[(size_t)b * H + h] = acc + bc[h];
    }
}

// ---------------------------------------------------------------------------
extern "C" void kernel_launch(void* const* d_in, const int* in_sizes, int n_in,
                              void* d_out, int out_size, void* d_ws, size_t ws_size,
                              hipStream_t stream) {
    const float* input = (const float*)d_in[0];
    const float* ctx   = (const float*)d_in[1];
    const float* amask = (const float*)d_in[2];
    const float* W_in  = (const float*)d_in[3];
    const float* b_in  = (const float*)d_in[4];
    const float* W_ctx = (const float*)d_in[5];
    const float* b_ctx = (const float*)d_in[6];
    const float* V     = (const float*)d_in[7];
    const int*   mask  = (const int*)d_in[8];

    float* out = (float*)d_out;
    float* hidden = out;            // [B,H]
    float* alpha  = out + B * H;    // [B,S]

    _Float16* wsB  = (_Float16*)d_ws;
    float*    part = (float*)((char*)d_ws + WS_PART_OFF);
    int*      cnt  = (int*)((char*)d_ws + WS_CNT_OFF);

    // K0: pack Wc -> fp16 fragment order (+ zero cnt); K0b: mask count
    k_pack_wc<<<dim3(128), dim3(256), 0, stream>>>(W_ctx, wsB, cnt);
    k_mask_count<<<dim3(64), dim3(256), 0, stream>>>(mask, cnt);

    // K1: inp staged in the hidden region (overwritten later by real hidden)
    k_input_linear<<<dim3(B), dim3(256), 0, stream>>>(input, W_in, b_in, hidden);

    // K2: fused energy GEMM -> att (alpha region, direct store)
    k_energy<<<dim3(B * S / 64), dim3(512), 0, stream>>>(
        ctx, wsB, b_ctx, hidden, V, alpha);

    // K4: mask branch + softmax in place -> alpha final
    k_softmax<<<dim3(B), dim3(256), 0, stream>>>(mask, amask, cnt, alpha);

    // K5: weighted context partial sums -> part (no atomics)
    k_wsum<<<dim3(16 * B), dim3(256), 0, stream>>>(ctx, alpha, part);

    // K6: hidden = Wc @ sum(part) + bc
    k_out<<<dim3(B), dim3(256), 0, stream>>>(part, W_ctx, b_ctx, hidden);
}

// Round 9
// 233.573 us; speedup vs baseline: 1.7571x; 1.0105x over previous
//
#include <hip/hip_runtime.h>
#include <math.h>

#define B 64
#define S 2048
#define D 512
#define H 512

#define BK 64    // k per barrier interval (2 MFMA sub-phases of 32)
#define WSC 128  // s-rows per k_wsum chunk

typedef _Float16 f16x8 __attribute__((ext_vector_type(8)));
typedef __fp16 fp16x2 __attribute__((ext_vector_type(2)));
typedef float f32x4 __attribute__((ext_vector_type(4)));

// ws layout: [0,512K) packed Wc fp16; [512K,512K+2M) wsum partials f32 [16][B][D];
//            then 4 B mask count
#define WS_PART_OFF (512 * 1024)
#define WS_CNT_OFF  (512 * 1024 + 2 * 1024 * 1024)

// ---------------------------------------------------------------------------
// K0: pack Wc (fp32 [H][D]) -> fp16 in MFMA-fragment order; also zero cnt.
//   slot = st*2048 + hg*64 + lane ; holds Wc[hg*16 + (lane&15)][st*32 + (lane>>4)*8 + j]
// ---------------------------------------------------------------------------
__global__ __launch_bounds__(256) void k_pack_wc(
        const float* __restrict__ Wc, _Float16* __restrict__ wsB,
        int* __restrict__ cnt) {
    if (blockIdx.x == 0 && threadIdx.x == 0) *cnt = 0;
    const int slot = blockIdx.x * 256 + threadIdx.x;   // 0..32767
    const int st   = slot >> 11;
    const int rem  = slot & 2047;
    const int hg   = rem >> 6;
    const int lane = rem & 63;
    const int h  = hg * 16 + (lane & 15);
    const int k0 = st * 32 + (lane >> 4) * 8;
    const float* src = Wc + (size_t)h * D + k0;
    float4 f0 = *(const float4*)src;
    float4 f1 = *(const float4*)(src + 4);
    f16x8 v;
    v[0] = (_Float16)f0.x; v[1] = (_Float16)f0.y;
    v[2] = (_Float16)f0.z; v[3] = (_Float16)f0.w;
    v[4] = (_Float16)f1.x; v[5] = (_Float16)f1.y;
    v[6] = (_Float16)f1.z; v[7] = (_Float16)f1.w;
    *(f16x8*)(wsB + (size_t)slot * 8) = v;
}

// ---------------------------------------------------------------------------
// K0b: global mask count (cnt pre-zeroed by k_pack_wc earlier on the stream)
// ---------------------------------------------------------------------------
__global__ __launch_bounds__(256) void k_mask_count(
        const int* __restrict__ mask, int* __restrict__ cnt) {
    const int base = blockIdx.x * 256 + threadIdx.x;
    int local = 0;
    for (int i = base; i < B * S; i += 256 * 64) local += (mask[i] != 0) ? 1 : 0;
    #pragma unroll
    for (int off = 32; off; off >>= 1) local += __shfl_down(local, off, 64);
    if ((threadIdx.x & 63) == 0 && local) atomicAdd(cnt, local);
}

// ---------------------------------------------------------------------------
// K1: inp = input @ W_in^T + b_in   -> staged in d_out hidden region
// ---------------------------------------------------------------------------
__global__ __launch_bounds__(256) void k_input_linear(
        const float* __restrict__ input,
        const float* __restrict__ W_in,
        const float* __restrict__ b_in,
        float* __restrict__ out_inp) {
    const int b = blockIdx.x;
    const int tid = threadIdx.x;
    __shared__ float xrow[D];
    for (int d = tid; d < D; d += 256) xrow[d] = input[(size_t)b * D + d];
    __syncthreads();
    for (int h = tid; h < H; h += 256) {
        const float* w = W_in + (size_t)h * D;
        float acc = 0.f;
        #pragma unroll 4
        for (int d = 0; d < D; d += 4) {
            float4 wv = *(const float4*)(w + d);
            acc += wv.x * xrow[d] + wv.y * xrow[d + 1] + wv.z * xrow[d + 2] + wv.w * xrow[d + 3];
        }
        out_inp[(size_t)b * H + h] = acc + b_in[h];
    }
}

// ---------------------------------------------------------------------------
// K2 (MFMA): fused ctx-GEMM + tanh + V-reduce.
//   Block: 64 s-rows x full H=512 (ctx read once). 8 waves, wave 64s x 64h.
//   A: 64x64 fp16 tile, XOR-swizzled 16B slots, double-buffered LDS, one
//   barrier per BK=64. B: packed-Wc global (L2) with ONE-SUB-PHASE REGISTER
//   PREFETCH (bcur/bnxt) so L2 latency hides under the MFMA cluster.
// ---------------------------------------------------------------------------
__global__ __launch_bounds__(512, 4) void k_energy(
        const float* __restrict__ ctx,
        const _Float16* __restrict__ WcP,
        const float* __restrict__ bc,
        const float* __restrict__ inp,
        const float* __restrict__ V,
        float* __restrict__ att) {
    __shared__ alignas(16) _Float16 Alds[2][64 * BK];   // 2 x 8 KB
    __shared__ float red[8][64];

    const int tid = threadIdx.x;
    const int b  = blockIdx.x >> 5;             // 32 s-tiles per batch
    const int s0 = (blockIdx.x & 31) << 6;

    // staging roles: 8 threads per row, 8 floats (16 B fp16) each
    const int arow = tid >> 3;      // 0..63
    const int akq  = tid & 7;       // 0..7 -> slot before swizzle
    const int wslot = akq ^ (arow & 7);
    // compute roles
    const int lane = tid & 63;
    const int w    = tid >> 6;      // 0..7: h-slice (64 h each)
    const int lrow = lane & 15;
    const int kblk = lane >> 4;     // 0..3

    f32x4 acc[4][4] = {};

    const float* ctx_src = ctx + ((size_t)b * S + s0 + arow) * D + akq * 8;
    const _Float16* Bbase = WcP + ((size_t)(w * 4) * 64 + lane) * 8;

    // ---- prologue: stage A(0) into buf 0 ----
    {
        float4 f0 = *(const float4*)ctx_src;
        float4 f1 = *(const float4*)(ctx_src + 4);
        union { fp16x2 h2[4]; f16x8 v; } u;
        u.h2[0] = __builtin_amdgcn_cvt_pkrtz(f0.x, f0.y);
        u.h2[1] = __builtin_amdgcn_cvt_pkrtz(f0.z, f0.w);
        u.h2[2] = __builtin_amdgcn_cvt_pkrtz(f1.x, f1.y);
        u.h2[3] = __builtin_amdgcn_cvt_pkrtz(f1.z, f1.w);
        *(f16x8*)&Alds[0][arow * BK + wslot * 8] = u.v;
    }

    // B(st=0) prefetch into bcur (before the barrier: independent of LDS)
    f16x8 bcur[4], bnxt[4];
    #pragma unroll
    for (int n = 0; n < 4; ++n)
        bcur[n] = *(const f16x8*)(Bbase + ((size_t)n * 64) * 8);

    __syncthreads();

    #pragma unroll 1
    for (int kt = 0; kt < 8; ++kt) {
        const int cur = kt & 1;
        const _Float16* Ab = &Alds[cur][0];

        // T14: issue next A tile global loads early
        float4 nf0, nf1;
        if (kt < 7) {
            nf0 = *(const float4*)(ctx_src + (kt + 1) * BK);
            nf1 = *(const float4*)(ctx_src + (kt + 1) * BK + 4);
        }

        // issue B(st = 2kt+1) into bnxt
        #pragma unroll
        for (int n = 0; n < 4; ++n)
            bnxt[n] = *(const f16x8*)(Bbase + ((size_t)(2 * kt + 1) * 2048 + n * 64) * 8);

        // ---- sub-phase 0: MFMAs with bcur ----
        {
            const int sl = kblk ^ (lrow & 7);
            f16x8 afr[4];
            #pragma unroll
            for (int m = 0; m < 4; ++m)
                afr[m] = *(const f16x8*)(Ab + (m * 16 + lrow) * BK + sl * 8);
            #pragma unroll
            for (int m = 0; m < 4; ++m)
                #pragma unroll
                for (int n = 0; n < 4; ++n)
                    acc[m][n] = __builtin_amdgcn_mfma_f32_16x16x32_f16(afr[m], bcur[n], acc[m][n], 0, 0, 0);
        }

        // issue B(st = 2kt+2) into bcur (next iteration's first sub-phase)
        if (kt < 7) {
            #pragma unroll
            for (int n = 0; n < 4; ++n)
                bcur[n] = *(const f16x8*)(Bbase + ((size_t)(2 * kt + 2) * 2048 + n * 64) * 8);
        }

        // ---- sub-phase 1: MFMAs with bnxt ----
        {
            const int sl = (4 + kblk) ^ (lrow & 7);
            f16x8 afr[4];
            #pragma unroll
            for (int m = 0; m < 4; ++m)
                afr[m] = *(const f16x8*)(Ab + (m * 16 + lrow) * BK + sl * 8);
            #pragma unroll
            for (int m = 0; m < 4; ++m)
                #pragma unroll
                for (int n = 0; n < 4; ++n)
                    acc[m][n] = __builtin_amdgcn_mfma_f32_16x16x32_f16(afr[m], bnxt[n], acc[m][n], 0, 0, 0);
        }

        // write next A tile to the other buffer
        if (kt < 7) {
            union { fp16x2 h2[4]; f16x8 v; } u;
            u.h2[0] = __builtin_amdgcn_cvt_pkrtz(nf0.x, nf0.y);
            u.h2[1] = __builtin_amdgcn_cvt_pkrtz(nf0.z, nf0.w);
            u.h2[2] = __builtin_amdgcn_cvt_pkrtz(nf1.x, nf1.y);
            u.h2[3] = __builtin_amdgcn_cvt_pkrtz(nf1.z, nf1.w);
            *(f16x8*)&Alds[cur ^ 1][arow * BK + wslot * 8] = u.v;
        }
        __syncthreads();
    }

    // ---- epilogue: tanh + V weighting; reduce over this wave's 64 h ----
    float ps[4][4] = {};   // [m][reg]
    #pragma unroll
    for (int n = 0; n < 4; ++n) {
        const int h = w * 64 + n * 16 + lrow;
        const float ib = inp[(size_t)b * H + h] + bc[h];
        const float v = V[h];
        #pragma unroll
        for (int m = 0; m < 4; ++m)
            #pragma unroll
            for (int r = 0; r < 4; ++r) {
                const float x = acc[m][n][r] + ib;
                const float t = 1.f - 2.f / (1.f + __expf(2.f * x));
                ps[m][r] += v * t;
            }
    }
    #pragma unroll
    for (int off = 1; off < 16; off <<= 1)
        #pragma unroll
        for (int m = 0; m < 4; ++m)
            #pragma unroll
            for (int r = 0; r < 4; ++r)
                ps[m][r] += __shfl_xor(ps[m][r], off, 64);
    if (lrow == 0) {
        #pragma unroll
        for (int m = 0; m < 4; ++m)
            #pragma unroll
            for (int r = 0; r < 4; ++r)
                red[w][m * 16 + kblk * 4 + r] = ps[m][r];
    }
    __syncthreads();
    if (tid < 64) {
        float sum = 0.f;
        #pragma unroll
        for (int i = 0; i < 8; ++i) sum += red[i][tid];
        att[(size_t)b * S + s0 + tid] = sum;
    }
}

// ---------------------------------------------------------------------------
// K4: mask branch + softmax per row (in place in the alpha region).
// ---------------------------------------------------------------------------
__global__ __launch_bounds__(256) void k_softmax(
        const int* __restrict__ mask,
        const float* __restrict__ amask,
        const int* __restrict__ cnt,
        float* __restrict__ att) {
    const int b = blockIdx.x;
    const int tid = threadIdx.x;
    __shared__ float sh[S];
    __shared__ float fredm[4];
    __shared__ float freds[4];

    const int n_true = *cnt;
    const bool inf_branch = (n_true > 0) && (n_true == S);

    const float NEG_INF = -__builtin_inff();
    for (int s = tid; s < S; s += 256) {
        const float raw = att[(size_t)b * S + s];
        float v;
        if (inf_branch)
            v = mask[(size_t)b * S + s] ? NEG_INF : raw;
        else
            v = raw * amask[(size_t)b * S + s];
        sh[s] = v;
    }
    __syncthreads();

    float mx = NEG_INF;
    for (int s = tid; s < S; s += 256) mx = fmaxf(mx, sh[s]);
    #pragma unroll
    for (int off = 32; off; off >>= 1) mx = fmaxf(mx, __shfl_down(mx, off, 64));
    if ((tid & 63) == 0) fredm[tid >> 6] = mx;
    __syncthreads();
    mx = fmaxf(fmaxf(fredm[0], fredm[1]), fmaxf(fredm[2], fredm[3]));

    float lsum = 0.f;
    for (int s = tid; s < S; s += 256) {
        const float e = expf(sh[s] - mx);
        sh[s] = e;
        lsum += e;
    }
    #pragma unroll
    for (int off = 32; off; off >>= 1) lsum += __shfl_down(lsum, off, 64);
    if ((tid & 63) == 0) freds[tid >> 6] = lsum;
    __syncthreads();
    const float total = freds[0] + freds[1] + freds[2] + freds[3];
    const float rinv = 1.f / total;

    for (int s = tid; s < S; s += 256)
        att[(size_t)b * S + s] = sh[s] * rinv;
}

// ---------------------------------------------------------------------------
// K5: part[chunk][b][:] = sum_{s in chunk} alpha[b,s] * ctx[b,s,:]
// ---------------------------------------------------------------------------
__global__ __launch_bounds__(256) void k_wsum(
        const float* __restrict__ ctx,
        const float* __restrict__ alpha,
        float* __restrict__ part) {
    const int chunk = blockIdx.x & 15;
    const int b = blockIdx.x >> 4;
    const int s0 = chunk * WSC;
    const int tid = threadIdx.x;
    __shared__ float al[WSC];
    if (tid < WSC) al[tid] = alpha[(size_t)b * S + s0 + tid];
    __syncthreads();

    const int half = tid >> 7;
    const int dq = (tid & 127) * 4;
    const float* base = ctx + ((size_t)b * S + s0 + half) * D + dq;
    float4 acc = {0.f, 0.f, 0.f, 0.f};
    #pragma unroll 4
    for (int i = 0; i < WSC / 2; ++i) {
        float4 v = *(const float4*)(base + (size_t)i * 2 * D);
        const float a = al[i * 2 + half];
        acc.x += a * v.x; acc.y += a * v.y; acc.z += a * v.z; acc.w += a * v.w;
    }
    __shared__ float cb[2][D];
    *(float4*)&cb[half][dq] = acc;
    __syncthreads();
    if (tid < 128) {
        const int d = tid * 4;
        float4 p0 = *(const float4*)&cb[0][d];
        float4 p1 = *(const float4*)&cb[1][d];
        float4 o = {p0.x + p1.x, p0.y + p1.y, p0.z + p1.z, p0.w + p1.w};
        *(float4*)(part + ((size_t)chunk * B + b) * D + d) = o;
    }
}

// ---------------------------------------------------------------------------
// K6: hidden = Wc @ (sum of partials) + bc   (tiny GEMV per batch)
// ---------------------------------------------------------------------------
__global__ __launch_bounds__(256) void k_out(
        const float* __restrict__ part,
        const float* __restrict__ Wc,
        const float* __restrict__ bc,
        float* __restrict__ hidden) {
    const int b = blockIdx.x;
    const int tid = threadIdx.x;
    __shared__ float cb[D];
    for (int d = tid; d < D; d += 256) {
        float s = 0.f;
        #pragma unroll
        for (int c = 0; c < 16; ++c)
            s += part[((size_t)c * B + b) * D + d];
        cb[d] = s;
    }
    __syncthreads();
    for (int h = tid; h < H; h += 256) {
        const float* w = Wc + (size_t)h * D;
        float acc = 0.f;
        #pragma unroll 4
        for (int d = 0; d < D; d += 4) {
            float4 wv = *(const float4*)(w + d);
            acc += wv.x * cb[d] + wv.y * cb[d + 1] + wv.z * cb[d + 2] + wv.w * cb[d + 3];
        }
        hidden[(size_t)b * H + h] = acc + bc[h];
    }
}

// ---------------------------------------------------------------------------
extern "C" void kernel_launch(void* const* d_in, const int* in_sizes, int n_in,
                              void* d_out, int out_size, void* d_ws, size_t ws_size,
                              hipStream_t stream) {
    const float* input = (const float*)d_in[0];
    const float* ctx   = (const float*)d_in[1];
    const float* amask = (const float*)d_in[2];
    const float* W_in  = (const float*)d_in[3];
    const float* b_in  = (const float*)d_in[4];
    const float* W_ctx = (const float*)d_in[5];
    const float* b_ctx = (const float*)d_in[6];
    const float* V     = (const float*)d_in[7];
    const int*   mask  = (const int*)d_in[8];

    float* out = (float*)d_out;
    float* hidden = out;            // [B,H]
    float* alpha  = out + B * H;    // [B,S]

    _Float16* wsB  = (_Float16*)d_ws;
    float*    part = (float*)((char*)d_ws + WS_PART_OFF);
    int*      cnt  = (int*)((char*)d_ws + WS_CNT_OFF);

    // K0: pack Wc -> fp16 fragment order (+ zero cnt); K0b: mask count
    k_pack_wc<<<dim3(128), dim3(256), 0, stream>>>(W_ctx, wsB, cnt);
    k_mask_count<<<dim3(64), dim3(256), 0, stream>>>(mask, cnt);

    // K1: inp staged in the hidden region (overwritten later by real hidden)
    k_input_linear<<<dim3(B), dim3(256), 0, stream>>>(input, W_in, b_in, hidden);

    // K2: fused energy GEMM -> att (alpha region, direct store)
    k_energy<<<dim3(B * S / 64), dim3(512), 0, stream>>>(
        ctx, wsB, b_ctx, hidden, V, alpha);

    // K4: mask branch + softmax in place -> alpha final
    k_softmax<<<dim3(B), dim3(256), 0, stream>>>(mask, amask, cnt, alpha);

    // K5: weighted context partial sums -> part (no atomics)
    k_wsum<<<dim3(16 * B), dim3(256), 0, stream>>>(ctx, alpha, part);

    // K6: hidden = Wc @ sum(part) + bc
    k_out<<<dim3(B), dim3(256), 0, stream>>>(part, W_ctx, b_ctx, hidden);
}